// Round 8
// baseline (154.424 us; speedup 1.0000x reference)
//
#include <hip/hip_runtime.h>
#include <hip/hip_bf16.h>
#include <stdint.h>

#define KDIM 512
#define OUT_F 512
#define BM 128           // rows per block
#define BK 64            // k per step
#define NSTEP 8          // KDIM / BK
#define NTHREADS 1024    // 16 waves, 4M x 4N

typedef __attribute__((ext_vector_type(8))) short short8;
typedef __attribute__((ext_vector_type(4))) float floatx4;

__device__ __forceinline__ ushort f2bf(float f) {
  uint32_t u = __builtin_bit_cast(uint32_t, f);
  uint32_t r = u + 0x7fffu + ((u >> 16) & 1u);   // RNE bf16
  return (ushort)(r >> 16);
}

typedef const __attribute__((address_space(1))) uint32_t* gas1_u32;
typedef __attribute__((address_space(3))) uint32_t* gas3_u32;

__device__ __forceinline__ void gload_lds16(const void* g, void* l) {
  __builtin_amdgcn_global_load_lds((gas1_u32)g, (gas3_u32)l, 16, 0, 0);
}

#define VMCNT2  asm volatile("s_waitcnt vmcnt(2)" ::: "memory")
#define VMCNT0  asm volatile("s_waitcnt vmcnt(0)" ::: "memory")
#define LGKM0   asm volatile("s_waitcnt lgkmcnt(0)" ::: "memory")
#define FENCE   __builtin_amdgcn_sched_barrier(0)
#define SBAR    __builtin_amdgcn_s_barrier()

// ---------------------------------------------------------------------------
// Prep: W_eff (512x512) bf16 as [kt(8)][o(512)][k(64)] with XOR swizzle baked
// in; GEMM stages each 64KB kt-slab linearly via global_load_lds, reads
// swizzled (G21: source perm == read perm, dest linear).
// ---------------------------------------------------------------------------
__global__ void quat_prep_kernel(const float* __restrict__ wr, const float* __restrict__ wi,
                                 const float* __restrict__ wj, const float* __restrict__ wk,
                                 ushort* __restrict__ Bimg) {
  int idx = blockIdx.x * 256 + threadIdx.x;
  if (idx >= 512 * 512) return;
  int o = idx >> 9;        // output-feature index
  int c = idx & 511;       // input-feature index
  int og = o >> 7, oo = o & 127, cg = c >> 7, cc = c & 127;
  static const int   blkT[16] = {0,1,2,3, 1,0,3,2, 2,3,0,1, 3,2,1,0};
  static const float sgnT[16] = {1.f,-1.f,-1.f,-1.f, 1.f,1.f,1.f,-1.f,
                                 1.f,-1.f,1.f,1.f,   1.f,1.f,-1.f,1.f};
  int sel = og * 4 + cg;
  const float* Ws;
  switch (blkT[sel]) {
    case 0: Ws = wr; break;
    case 1: Ws = wi; break;
    case 2: Ws = wj; break;
    default: Ws = wk; break;
  }
  float v = sgnT[sel] * Ws[oo * 128 + cc];
  int kt = c >> 6, k = c & 63;
  int dst = kt * (OUT_F * BK) + o * BK + (k ^ ((o & 7) << 3));
  Bimg[dst] = f2bf(v);
}

// ---------------------------------------------------------------------------
// GEMM: out[M,512] = X[M,512] * W_eff^T (+bias)
// Block = 128 rows x ALL 512 cols. BK=64 -> 8 steps, counted-vmcnt pipeline
// (B(t+1) staged during compute(t), A 2-deep reg-prefetch, never vmcnt(0)
// in-loop). Epilogue: stage fp32 tile through LDS (reuse Bs), store as
// fully-coalesced nontemporal float4 (fixes 27% write amplification seen
// with scalar 64B-segment stores).
// ---------------------------------------------------------------------------
__global__ void __launch_bounds__(NTHREADS, 4)
quat_gemm_kernel(const float* __restrict__ X, const ushort* __restrict__ Bimg,
                 const float* __restrict__ bias, float* __restrict__ Out) {
  __shared__ __align__(16) ushort As[2][BM * BK];      // 2 x 16 KB
  __shared__ __align__(16) ushort Bs[2][OUT_F * BK];   // 2 x 64 KB

  const int bid = blockIdx.x;
  const size_t row0 = (size_t)bid * BM;
  const int tid = threadIdx.x, lane = tid & 63, wid = tid >> 6;
  const int lrow = lane & 15;
  const int lg   = lane >> 4;
  const int wm = wid >> 2, wn = wid & 3;     // 4M x 4N wave grid

  const int ar = tid >> 3;                   // A row [0,128)
  const int ac = (tid & 7) * 8;              // A col [0,64) step 8

  float4 av[2][2];                           // 2-deep A prefetch, 8 floats each

  auto issueA = [&](int t, int p) {
    const float* s = X + (row0 + ar) * KDIM + t * BK + ac;
    av[p][0] = *reinterpret_cast<const float4*>(s);
    av[p][1] = *reinterpret_cast<const float4*>(s + 4);
  };
  auto writeA = [&](int p, ushort* Ab) {
    short8 o;
    o[0] = (short)f2bf(av[p][0].x); o[1] = (short)f2bf(av[p][0].y);
    o[2] = (short)f2bf(av[p][0].z); o[3] = (short)f2bf(av[p][0].w);
    o[4] = (short)f2bf(av[p][1].x); o[5] = (short)f2bf(av[p][1].y);
    o[6] = (short)f2bf(av[p][1].z); o[7] = (short)f2bf(av[p][1].w);
    *reinterpret_cast<short8*>(Ab + ar * BK + (ac ^ ((ar & 7) << 3))) = o;
  };
  auto stageB = [&](int t, ushort* Bb) {     // 64KB: 16 waves x 4KB
    const ushort* s = Bimg + t * (OUT_F * BK) + wid * 2048 + lane * 8;
    ushort* d = Bb + wid * 2048;
#pragma unroll
    for (int i = 0; i < 4; ++i)
      gload_lds16(s + i * 512, d + i * 512);
  };

  floatx4 acc[2][8];
#pragma unroll
  for (int m = 0; m < 2; ++m)
#pragma unroll
    for (int n = 0; n < 8; ++n) acc[m][n] = {0.f, 0.f, 0.f, 0.f};

  auto compute = [&](const ushort* Ab, const ushort* Bb) {
#pragma unroll
    for (int kh = 0; kh < 2; ++kh) {
      const int kb = kh * 32 + lg * 8;
      short8 af[2];
#pragma unroll
      for (int m = 0; m < 2; ++m) {
        int row = wm * 32 + m * 16 + lrow;
        af[m] = *reinterpret_cast<const short8*>(Ab + row * BK + (kb ^ ((row & 7) << 3)));
      }
#pragma unroll
      for (int n = 0; n < 8; ++n) {
        int col = wn * 128 + n * 16 + lrow;
        short8 bf = *reinterpret_cast<const short8*>(Bb + col * BK + (kb ^ ((col & 7) << 3)));
        acc[0][n] = __builtin_amdgcn_mfma_f32_16x16x32_bf16(af[0], bf, acc[0][n], 0, 0, 0);
        acc[1][n] = __builtin_amdgcn_mfma_f32_16x16x32_bf16(af[1], bf, acc[1][n], 0, 0, 0);
      }
    }
  };

  // ---- prologue ----
  issueA(0, 0);
  stageB(0, Bs[0]);
  issueA(1, 1);
  writeA(0, As[0]);        // compiler inserts counted wait for A(0) regs
  VMCNT2; FENCE;           // B(0) in LDS; A(1) stays in flight
  LGKM0; SBAR;

  // ---- steady steps t = 0..5: stage B(t+1), prefetch A(t+2) ----
#define STEP_MAIN(T)                                        \
  {                                                         \
    stageB((T) + 1, Bs[((T) & 1) ^ 1]);                     \
    issueA((T) + 2, (T) & 1);                               \
    writeA(((T) + 1) & 1, (ushort*)As[((T) & 1) ^ 1]);      \
    compute(As[(T) & 1], Bs[(T) & 1]);                      \
    VMCNT2; FENCE;                                          \
    LGKM0; SBAR;                                            \
  }
  STEP_MAIN(0) STEP_MAIN(1) STEP_MAIN(2)
  STEP_MAIN(3) STEP_MAIN(4) STEP_MAIN(5)
#undef STEP_MAIN

  // t = 6: stage B(7), no A(8)
  {
    stageB(7, Bs[1]);
    writeA(1, (ushort*)As[1]);
    compute(As[0], Bs[0]);
    VMCNT0; FENCE;
    LGKM0; SBAR;
  }
  // t = 7: compute only
  compute(As[1], Bs[1]);

  // ---- epilogue: LDS-staged, fully-coalesced nontemporal float4 stores ----
  float bv[8];
#pragma unroll
  for (int n = 0; n < 8; ++n) bv[n] = bias[wn * 128 + n * 16 + lrow];

  float* lds = reinterpret_cast<float*>(&Bs[0][0]);   // 128 KB staging
  float* Ob = Out + row0 * OUT_F;

#pragma unroll
  for (int pass = 0; pass < 2; ++pass) {
    __syncthreads();                    // staging region free
    if ((wm >> 1) == pass) {            // 8 waves deposit their 32x128 tiles
      float* slab = lds + ((wm & 1) * 4 + wn) * 4096;   // 16 KB each
#pragma unroll
      for (int n = 0; n < 8; ++n)
#pragma unroll
        for (int m = 0; m < 2; ++m)
#pragma unroll
          for (int j = 0; j < 4; ++j)
            slab[(m * 16 + lg * 4 + j) * 128 + n * 16 + lrow] = acc[m][n][j] + bv[n];
    }
    __syncthreads();
    // all 1024 threads store 64 rows x 512 cols linearly (1KB/wave-instr)
#pragma unroll
    for (int i = 0; i < 8; ++i) {
      int f4 = i * 1024 + tid;          // float4 index in 64x512 half-tile
      int rl = f4 >> 7;                 // local row [0,64)
      int c4 = f4 & 127;                // float4-col [0,128)
      floatx4 v = *reinterpret_cast<const floatx4*>(
          lds + ((rl >> 5) * 4 + (c4 >> 5)) * 4096 + (rl & 31) * 128 + (c4 & 31) * 4);
      __builtin_nontemporal_store(
          v, reinterpret_cast<floatx4*>(Ob + (size_t)(pass * 64 + rl) * OUT_F + c4 * 4));
    }
  }
}

extern "C" void kernel_launch(void* const* d_in, const int* in_sizes, int n_in,
                              void* d_out, int out_size, void* d_ws, size_t ws_size,
                              hipStream_t stream) {
  const float* x    = (const float*)d_in[0];
  const float* wr   = (const float*)d_in[1];
  const float* wi   = (const float*)d_in[2];
  const float* wj   = (const float*)d_in[3];
  const float* wk   = (const float*)d_in[4];
  const float* bias = (const float*)d_in[5];
  float* out = (float*)d_out;
  ushort* Bimg = (ushort*)d_ws;         // 512 KB

  int M = in_sizes[0] / KDIM;           // 131072
  int nwg = M / BM;                     // 1024

  hipLaunchKernelGGL(quat_prep_kernel, dim3((512 * 512 + 255) / 256), dim3(256), 0, stream,
                     wr, wi, wj, wk, Bimg);
  hipLaunchKernelGGL(quat_gemm_kernel, dim3(nwg), dim3(NTHREADS), 0, stream,
                     x, Bimg, bias, out);
}